// Round 2
// baseline (299.030 us; speedup 1.0000x reference)
//
#include <hip/hip_runtime.h>
#include <hip/hip_bf16.h>

#define N_NODES 100000
#define E_EDGES 1600000
#define IN_C 128
#define HID_C 64
#define OUT_C 40

#define NBUCK 196          // ceil(100000 / 512) buckets by dst>>9
#define BCAP 9216          // mean 8192 + 11 sigma
#define B1_EPT 16
#define B1_CHUNK (256 * B1_EPT)   // 4096 edges per block
#define B1_GRID ((E_EDGES + B1_CHUNK - 1) / B1_CHUNK)
#define TILE_GRID ((N_NODES + 63) / 64)
#define ECAP 384           // per-wave csr segment cache (mean 256 + 8 sigma)

typedef unsigned short ushort_t;
typedef unsigned int uint_t;
typedef unsigned char uchar_t;
typedef __attribute__((ext_vector_type(8))) short bf16x8;
typedef __attribute__((ext_vector_type(4))) float f32x4;
typedef __attribute__((ext_vector_type(2))) float f32x2;

__device__ __forceinline__ float bfu2f(ushort_t u) {
    return __uint_as_float(((uint_t)u) << 16);
}
__device__ __forceinline__ ushort_t f2bfu(float f) {   // RNE
    uint_t u = __float_as_uint(f);
    return (ushort_t)((u + 0x7FFFu + ((u >> 16) & 1u)) >> 16);
}
__device__ __forceinline__ uchar_t f2fp8(float f) {    // e4m3 via HW cvt
    int p = __builtin_amdgcn_cvt_pk_fp8_f32(f, f, 0, false);
    return (uchar_t)(p & 0xff);
}

// accumulate 8 fp8 values (one uint2) into 4 packed-f32 accumulators
#define ACC8(A, U)                                                   \
    do {                                                             \
        (A)[0] += __builtin_amdgcn_cvt_pk_f32_fp8((U).x, false);     \
        (A)[1] += __builtin_amdgcn_cvt_pk_f32_fp8((U).x, true);      \
        (A)[2] += __builtin_amdgcn_cvt_pk_f32_fp8((U).y, false);     \
        (A)[3] += __builtin_amdgcn_cvt_pk_f32_fp8((U).y, true);      \
    } while (0)

// accumulate 16 fp8 values (one uint4) into 8 packed-f32 accumulators
#define ACC16(A, U)                                                  \
    do {                                                             \
        (A)[0] += __builtin_amdgcn_cvt_pk_f32_fp8((U).x, false);     \
        (A)[1] += __builtin_amdgcn_cvt_pk_f32_fp8((U).x, true);      \
        (A)[2] += __builtin_amdgcn_cvt_pk_f32_fp8((U).y, false);     \
        (A)[3] += __builtin_amdgcn_cvt_pk_f32_fp8((U).y, true);      \
        (A)[4] += __builtin_amdgcn_cvt_pk_f32_fp8((U).z, false);     \
        (A)[5] += __builtin_amdgcn_cvt_pk_f32_fp8((U).z, true);      \
        (A)[6] += __builtin_amdgcn_cvt_pk_f32_fp8((U).w, false);     \
        (A)[7] += __builtin_amdgcn_cvt_pk_f32_fp8((U).w, true);      \
    } while (0)

// ================================================================ K1: bucket (blocks 0..B1_GRID-1) || wprep (rest)
__global__ __launch_bounds__(256) void k_prep(const int* __restrict__ src, const int* __restrict__ dst,
                                              int* __restrict__ bcur, int* __restrict__ bucket,
                                              const float* __restrict__ Wl1, const float* __restrict__ Wr1,
                                              const float* __restrict__ Wl2, const float* __restrict__ Wr2,
                                              ushort_t* __restrict__ Wt1, ushort_t* __restrict__ Wt2) {
    __shared__ int cnt[NBUCK];
    __shared__ int base[NBUCK];
    const int t = threadIdx.x;

    if (blockIdx.x < B1_GRID) {
        // ---- bucketize edges by dst>>9 (packed: src | dlocal<<17)
        const int e0 = blockIdx.x * B1_CHUNK;
        for (int i = t; i < NBUCK; i += 256) cnt[i] = 0;
        __syncthreads();

        int myp[B1_EPT];
        int myb[B1_EPT];
#pragma unroll
        for (int j = 0; j < B1_EPT; ++j) {
            int e = e0 + t + j * 256;
            if (e < E_EDGES) {
                int d = dst[e];
                myp[j] = src[e] | ((d & 511) << 17);
                myb[j] = d >> 9;
                atomicAdd(&cnt[myb[j]], 1);
            } else {
                myb[j] = -1;
            }
        }
        __syncthreads();
        for (int i = t; i < NBUCK; i += 256) {
            base[i] = atomicAdd(&bcur[i], cnt[i]);
            cnt[i] = 0;
        }
        __syncthreads();
#pragma unroll
        for (int j = 0; j < B1_EPT; ++j) {
            if (myb[j] >= 0) {
                int b = myb[j];
                int loc = atomicAdd(&cnt[b], 1);
                int pos = base[b] + loc;
                if (pos < BCAP) bucket[(size_t)b * BCAP + pos] = myp[j];
            }
        }
    } else {
        // ---- weight prep: bf16, transposed, l|r concatenated
        int i = (blockIdx.x - B1_GRID) * 256 + t;
        if (i < 128 * 128) {
            int n = i >> 7, k = i & 127;
            float v = (n < 64) ? Wl1[k * 64 + n] : Wr1[k * 64 + (n - 64)];
            Wt1[n * 128 + k] = f2bfu(v);
        }
        if (i < 80 * 64) {
            int n = i >> 6, k = i & 63;
            float v = (n < 40) ? Wl2[k * 40 + n] : Wr2[k * 40 + (n - 40)];
            Wt2[n * 64 + k] = f2bfu(v);
        }
    }
}

// ================================================================ K2: csr (blocks 0..NBUCK-1) || gemm1 (rest)
struct SmemCsr {
    int red[256];
    int hist[512];
    int sc[2][512];
    int cur[512];
    int csrbuf[BCAP];
};
struct SmemGemm1 {
    ushort_t xs[64 * 136];
    ushort_t wsm[128 * 136];
};
union SmemK2 {
    SmemCsr c;
    SmemGemm1 g;
};

__global__ __launch_bounds__(256) void k_csr_gemm1(const int* __restrict__ bucket, const int* __restrict__ bcur,
                                                   int* __restrict__ rowptr, int* __restrict__ csr,
                                                   const float* __restrict__ x, const ushort_t* __restrict__ Wt,
                                                   uchar_t* __restrict__ h1l, ushort_t* __restrict__ h1r) {
    __shared__ SmemK2 sm;
    const int t = threadIdx.x;

    if (blockIdx.x < NBUCK) {
        // ---- per-bucket counting sort -> rowptr slice + csr slice (csr stores node INDEX)
        const int b = blockIdx.x;
        const int n0 = b << 9;
        const int nb = min(512, N_NODES - n0);
        const int sz = min(bcur[b], BCAP);
        const int* bdata = bucket + (size_t)b * BCAP;

        int v = (t < b) ? min(bcur[t], BCAP) : 0;   // NBUCK=196 <= 256
        sm.c.red[t] = v;
        __syncthreads();
        for (int off = 128; off > 0; off >>= 1) {
            if (t < off) sm.c.red[t] += sm.c.red[t + off];
            __syncthreads();
        }
        const int cbase = sm.c.red[0];

        for (int i = t; i < 512; i += 256) sm.c.hist[i] = 0;
        __syncthreads();
        for (int i = t; i < sz; i += 256) {
            int p = bdata[i];
            atomicAdd(&sm.c.hist[p >> 17], 1);
        }
        __syncthreads();
        for (int i = t; i < 512; i += 256) sm.c.sc[0][i] = sm.c.hist[i];
        __syncthreads();
        int pp = 0;
        for (int off = 1; off < 512; off <<= 1) {
            for (int i = t; i < 512; i += 256)
                sm.c.sc[1 - pp][i] = sm.c.sc[pp][i] + ((i >= off) ? sm.c.sc[pp][i - off] : 0);
            __syncthreads();
            pp ^= 1;
        }
        for (int i = t; i < 512; i += 256) {
            int exc = sm.c.sc[pp][i] - sm.c.hist[i];
            sm.c.cur[i] = exc;
            if (i < nb) rowptr[n0 + i] = cbase + exc;
        }
        __syncthreads();
        for (int i = t; i < sz; i += 256) {
            int p = bdata[i];
            int pos = atomicAdd(&sm.c.cur[p >> 17], 1);
            sm.c.csrbuf[pos] = p & 0x1FFFF;          // plain src node index
        }
        __syncthreads();
        for (int i = t; i < sz; i += 256)
            csr[cbase + i] = sm.c.csrbuf[i];
        if (b == NBUCK - 1 && t == 0) rowptr[N_NODES] = cbase + sz;
    } else {
        // ---- GEMM1 (MFMA): [h1l(fp8) | h1r(bf16)] = x @ [Wl1|Wr1]
        const int row_base = (blockIdx.x - NBUCK) * 64;

        for (int i = t; i < 128 * 16; i += 256) {
            int n = i >> 4, seg = i & 15;
            uint4 v = *(const uint4*)(Wt + n * 128 + seg * 8);
            *(uint4*)(sm.g.wsm + n * 136 + seg * 8) = v;
        }
        for (int i = t; i < 64 * 32; i += 256) {
            int row = i >> 5, seg = i & 31;
            int gr = row_base + row;
            float4 v = make_float4(0.f, 0.f, 0.f, 0.f);
            if (gr < N_NODES) v = *(const float4*)(x + (size_t)gr * IN_C + seg * 4);
            ushort4 u;
            u.x = f2bfu(v.x); u.y = f2bfu(v.y); u.z = f2bfu(v.z); u.w = f2bfu(v.w);
            *(ushort4*)(sm.g.xs + row * 136 + seg * 4) = u;
        }
        __syncthreads();

        const int wv = t >> 6, lane = t & 63;
        const int m = lane & 15, quad = lane >> 4;
        const int m0 = wv * 16;

        bf16x8 a[4];
#pragma unroll
        for (int kk = 0; kk < 4; ++kk)
            a[kk] = *(const bf16x8*)(sm.g.xs + (m0 + m) * 136 + kk * 32 + quad * 8);

        f32x4 acc[8];
#pragma unroll
        for (int nt = 0; nt < 8; ++nt) acc[nt] = (f32x4){0.f, 0.f, 0.f, 0.f};

#pragma unroll
        for (int nt = 0; nt < 8; ++nt) {
#pragma unroll
            for (int kk = 0; kk < 4; ++kk) {
                bf16x8 b = *(const bf16x8*)(sm.g.wsm + (nt * 16 + m) * 136 + kk * 32 + quad * 8);
                acc[nt] = __builtin_amdgcn_mfma_f32_16x16x32_bf16(a[kk], b, acc[nt], 0, 0, 0);
            }
        }

        const int grow_base = row_base + m0 + quad * 4;
#pragma unroll
        for (int r = 0; r < 4; ++r) {
            int grow = grow_base + r;
            if (grow < N_NODES) {
#pragma unroll
                for (int nt = 0; nt < 4; ++nt)
                    h1l[(size_t)grow * HID_C + nt * 16 + m] = f2fp8(acc[nt][r]);
#pragma unroll
                for (int nt = 4; nt < 8; ++nt)
                    h1r[(size_t)grow * HID_C + (nt - 4) * 16 + m] = f2bfu(acc[nt][r]);
            }
        }
    }
}

// ================================================================ K3: fused agg1 + gemm2
// Phase A: 4 waves x 16 serial rows. The wave's 16 rows own a CONTIGUOUS csr segment:
//   preload it into per-wave LDS once (coalesced) -> csr global latency off the per-round chain.
//   16-slot uint4 gather: lane = slot(0..15) x part(0..3), 16B/lane -> 16 edges/round
//   (typical row = ONE round). relu(mean+root+b1) -> LDS bf16 tile.
// Phase B: gemm2 MFMA from LDS: [h2l(fp8,stride64) | h2r(bf16)] = hid @ [Wl2|Wr2]
__global__ __launch_bounds__(256) void k_agg1_gemm2(const int* __restrict__ rowptr, const int* __restrict__ csr,
                                                    const uchar_t* __restrict__ h1l, const ushort_t* __restrict__ h1r,
                                                    const float* __restrict__ b1, const ushort_t* __restrict__ Wt,
                                                    uchar_t* __restrict__ h2l, ushort_t* __restrict__ h2r) {
    __shared__ ushort_t hs[64 * 72];     // hid tile, bf16
    __shared__ ushort_t wsm[80 * 72];    // Wt2
    __shared__ int ecache[4][ECAP];      // per-wave csr segment cache
    const int t = threadIdx.x;
    const int row_base = blockIdx.x * 64;
    const int wv = t >> 6, lane = t & 63;
    const int slot16 = lane >> 2;
    const int part4 = lane & 3;

    // stage Wt2 (consumed after the phase-boundary syncthreads)
    for (int i = t; i < 80 * 8; i += 256) {
        int n = i >> 3, seg = i & 7;
        uint4 v = *(const uint4*)(Wt + n * 64 + seg * 8);
        *(uint4*)(wsm + n * 72 + seg * 8) = v;
    }

    // ---- phase A: aggregate 16 rows per wave
    // bias: lanes 0..3 hold channels lane*16 .. lane*16+15
    float bv[16];
    if (lane < 4) {
#pragma unroll
        for (int q = 0; q < 4; ++q) {
            float4 b4 = *(const float4*)(b1 + lane * 16 + q * 4);
            bv[4 * q + 0] = b4.x; bv[4 * q + 1] = b4.y;
            bv[4 * q + 2] = b4.z; bv[4 * q + 3] = b4.w;
        }
    }

    // preload the wave's 17 rowptr entries once; broadcast per-row below
    const int row0 = row_base + wv * 16;
    int rpv = 0;
    if (lane < 17) rpv = rowptr[min(row0 + lane, N_NODES)];
    const int seg_start = __shfl(rpv, 0);
    const int seg_end = __shfl(rpv, 16);
    const int seg_len = seg_end - seg_start;
    const bool fits = (seg_len <= ECAP);
    {
        int ld = min(seg_len, ECAP);
        for (int i = lane; i < ld; i += 64)
            ecache[wv][i] = csr[seg_start + i];
    }

    for (int r16 = 0; r16 < 16; ++r16) {
        const int lrow = wv * 16 + r16;
        const int row = row0 + r16;
        if (row >= N_NODES) {
            if (lane < 4) {
                uint4 z = make_uint4(0u, 0u, 0u, 0u);
                *(uint4*)(hs + lrow * 72 + lane * 16) = z;
                *(uint4*)(hs + lrow * 72 + lane * 16 + 8) = z;
            }
            continue;
        }
        const int start = __shfl(rpv, r16);
        const int end = __shfl(rpv, r16 + 1);

        f32x2 acc[8];
#pragma unroll
        for (int j = 0; j < 8; ++j) acc[j] = (f32x2){0.f, 0.f};

        if (fits) {
            const int lo = start - seg_start, hi = end - seg_start;
            int base = lo;
            for (; base + 16 <= hi; base += 16) {
                int s = ecache[wv][base + slot16];
                uint4 u = *(const uint4*)(h1l + ((size_t)s << 6) + part4 * 16);
                ACC16(acc, u);
            }
            if (base < hi) {
                int e = base + slot16;
                int s = ecache[wv][min(e, hi - 1)];
                uint4 u = *(const uint4*)(h1l + ((size_t)s << 6) + part4 * 16);
                if (e >= hi) { u.x = 0u; u.y = 0u; u.z = 0u; u.w = 0u; }
                ACC16(acc, u);
            }
        } else {
            // rare fallback: segment exceeded cache, read csr directly
            int base = start;
            for (; base + 16 <= end; base += 16) {
                int s = csr[base + slot16];
                uint4 u = *(const uint4*)(h1l + ((size_t)s << 6) + part4 * 16);
                ACC16(acc, u);
            }
            if (base < end) {
                int e = base + slot16;
                int s = csr[min(e, end - 1)];
                uint4 u = *(const uint4*)(h1l + ((size_t)s << 6) + part4 * 16);
                if (e >= end) { u.x = 0u; u.y = 0u; u.z = 0u; u.w = 0u; }
                ACC16(acc, u);
            }
        }

        // reduce over the 16 slots (xor 4,8,16,32)
#pragma unroll
        for (int off = 4; off <= 32; off <<= 1) {
#pragma unroll
            for (int j = 0; j < 8; ++j) {
                f32x2 tt;
                tt.x = __shfl_xor(acc[j].x, off);
                tt.y = __shfl_xor(acc[j].y, off);
                acc[j] += tt;
            }
        }

        if (lane < 4) {
            float inv = __builtin_amdgcn_rcpf(fmaxf((float)(end - start), 1.0f));
            ushort_t rr[16];
            *(uint4*)&rr[0] = *(const uint4*)(h1r + (size_t)row * HID_C + lane * 16);
            *(uint4*)&rr[8] = *(const uint4*)(h1r + (size_t)row * HID_C + lane * 16 + 8);
            ushort_t o[16];
#pragma unroll
            for (int j = 0; j < 8; ++j) {
                o[2 * j]     = f2bfu(fmaxf(acc[j].x * inv + bfu2f(rr[2 * j])     + bv[2 * j],     0.f));
                o[2 * j + 1] = f2bfu(fmaxf(acc[j].y * inv + bfu2f(rr[2 * j + 1]) + bv[2 * j + 1], 0.f));
            }
            *(uint4*)(hs + lrow * 72 + lane * 16) = *(const uint4*)&o[0];
            *(uint4*)(hs + lrow * 72 + lane * 16 + 8) = *(const uint4*)&o[8];
        }
    }
    __syncthreads();

    // ---- phase B: gemm2 MFMA from LDS
    const int m = lane & 15, quad = lane >> 4;
    const int m0 = wv * 16;

    bf16x8 a[2];
#pragma unroll
    for (int kk = 0; kk < 2; ++kk)
        a[kk] = *(const bf16x8*)(hs + (m0 + m) * 72 + kk * 32 + quad * 8);

    f32x4 acc[5];
#pragma unroll
    for (int nt = 0; nt < 5; ++nt) acc[nt] = (f32x4){0.f, 0.f, 0.f, 0.f};

#pragma unroll
    for (int nt = 0; nt < 5; ++nt) {
#pragma unroll
        for (int kk = 0; kk < 2; ++kk) {
            bf16x8 b = *(const bf16x8*)(wsm + (nt * 16 + m) * 72 + kk * 32 + quad * 8);
            acc[nt] = __builtin_amdgcn_mfma_f32_16x16x32_bf16(a[kk], b, acc[nt], 0, 0, 0);
        }
    }

    const int grow_base = row_base + m0 + quad * 4;
#pragma unroll
    for (int r = 0; r < 4; ++r) {
        int grow = grow_base + r;
        if (grow < N_NODES) {
#pragma unroll
            for (int nt = 0; nt < 5; ++nt) {
                int col = nt * 16 + m;
                float v = acc[nt][r];
                if (col < OUT_C) h2l[(size_t)grow * 64 + col] = f2fp8(v);
                else             h2r[(size_t)grow * OUT_C + (col - OUT_C)] = f2bfu(v);
            }
        }
    }
}

// ================================================================ agg2: 8-slot uint2 gather of fp8 h2l (stride-64 rows)
// csr stores node index -> byte offset = s<<6. Dual 16-edge rounds keep 2 gathers in flight.
__global__ __launch_bounds__(256) void k_agg2(const int* __restrict__ rowptr, const int* __restrict__ csr,
                                              const uchar_t* __restrict__ h2l, const ushort_t* __restrict__ h2r,
                                              const float* __restrict__ b2, float* __restrict__ out) {
    int row = (blockIdx.x * 256 + threadIdx.x) >> 6;
    int lane = threadIdx.x & 63;
    if (row >= N_NODES) return;
    int2 rp = *(const int2*)(rowptr + row);
    int start = rp.x, end = rp.y;
    const int slot = lane >> 3;
    const int part = lane & 7;
    f32x2 acc[4];
#pragma unroll
    for (int j = 0; j < 4; ++j) acc[j] = (f32x2){0.f, 0.f};

    int base = start;
    for (; base + 16 <= end; base += 16) {
        int s0 = csr[base + slot];
        int s1 = csr[base + slot + 8];
        uint2 u0 = *(const uint2*)(h2l + ((size_t)s0 << 6) + part * 8);
        uint2 u1 = *(const uint2*)(h2l + ((size_t)s1 << 6) + part * 8);
        ACC8(acc, u0);
        ACC8(acc, u1);
    }
    if (base + 8 <= end) {
        int s0 = csr[base + slot];
        uint2 u0 = *(const uint2*)(h2l + ((size_t)s0 << 6) + part * 8);
        ACC8(acc, u0);
        base += 8;
    }
    if (base < end) {
        int e = base + slot;
        int s = csr[min(e, end - 1)];
        uint2 u = *(const uint2*)(h2l + ((size_t)s << 6) + part * 8);
        if (e >= end) { u.x = 0u; u.y = 0u; }
        ACC8(acc, u);
    }
#pragma unroll
    for (int off = 8; off <= 32; off <<= 1) {
#pragma unroll
        for (int j = 0; j < 4; ++j) {
            f32x2 tt;
            tt.x = __shfl_xor(acc[j].x, off);
            tt.y = __shfl_xor(acc[j].y, off);
            acc[j] += tt;
        }
    }

    // slot-0 lanes with part<5 hold channels part*8 .. part*8+7
    const bool fin = (slot == 0) && (part < 5);
    float inv = __builtin_amdgcn_rcpf(fmaxf((float)(end - start), 1.0f));
    f32x2 v2[4];
    if (fin) {
        size_t bi = (size_t)row * OUT_C + part * 8;
        ushort_t rr[8];
        *(uint2*)&rr[0] = *(const uint2*)(h2r + bi);
        *(uint2*)&rr[4] = *(const uint2*)(h2r + bi + 4);
        float4 bb0 = *(const float4*)(b2 + part * 8);
        float4 bb1 = *(const float4*)(b2 + part * 8 + 4);
        v2[0] = (f32x2){acc[0].x * inv + bfu2f(rr[0]) + bb0.x, acc[0].y * inv + bfu2f(rr[1]) + bb0.y};
        v2[1] = (f32x2){acc[1].x * inv + bfu2f(rr[2]) + bb0.z, acc[1].y * inv + bfu2f(rr[3]) + bb0.w};
        v2[2] = (f32x2){acc[2].x * inv + bfu2f(rr[4]) + bb1.x, acc[2].y * inv + bfu2f(rr[5]) + bb1.y};
        v2[3] = (f32x2){acc[3].x * inv + bfu2f(rr[6]) + bb1.z, acc[3].y * inv + bfu2f(rr[7]) + bb1.w};
    } else {
#pragma unroll
        for (int j = 0; j < 4; ++j) v2[j] = (f32x2){-1e30f, -1e30f};
    }
    // softmax stats within the 8-lane group (non-fin lanes compute garbage, never write)
    f32x2 m2;
    m2.x = fmaxf(fmaxf(v2[0].x, v2[1].x), fmaxf(v2[2].x, v2[3].x));
    m2.y = fmaxf(fmaxf(v2[0].y, v2[1].y), fmaxf(v2[2].y, v2[3].y));
    float pm = fmaxf(m2.x, m2.y);
#pragma unroll
    for (int off = 1; off <= 4; off <<= 1) pm = fmaxf(pm, __shfl_xor(pm, off));
    float es = 0.f;
#pragma unroll
    for (int j = 0; j < 4; ++j) {
        es += __expf(v2[j].x - pm);
        es += __expf(v2[j].y - pm);
    }
#pragma unroll
    for (int off = 1; off <= 4; off <<= 1) es += __shfl_xor(es, off);
    float ls = __logf(es);
    if (fin) {
        size_t bo = (size_t)row * OUT_C + part * 8;
        *(float4*)(out + bo) = make_float4(v2[0].x - pm - ls, v2[0].y - pm - ls,
                                           v2[1].x - pm - ls, v2[1].y - pm - ls);
        *(float4*)(out + bo + 4) = make_float4(v2[2].x - pm - ls, v2[2].y - pm - ls,
                                               v2[3].x - pm - ls, v2[3].y - pm - ls);
    }
}

// ----------------------------------------------------------------
extern "C" void kernel_launch(void* const* d_in, const int* in_sizes, int n_in,
                              void* d_out, int out_size, void* d_ws, size_t ws_size,
                              hipStream_t stream) {
    const float* x   = (const float*)d_in[0];
    const int*   ei  = (const int*)d_in[1];
    const float* Wl1 = (const float*)d_in[2];
    const float* b1  = (const float*)d_in[3];
    const float* Wr1 = (const float*)d_in[4];
    const float* Wl2 = (const float*)d_in[5];
    const float* b2  = (const float*)d_in[6];
    const float* Wr2 = (const float*)d_in[7];

    // ws layout (4B units): bucket int[196*9216] | bcur | rowptr[N+1] | csr[E] | [align16] |
    //   Wt1 bf16[128*128] | Wt2 bf16[80*64] | h1l fp8[N*64] | h1r bf16[N*64] |
    //   h2l fp8[N*64] | h2r bf16[N*40]
    size_t u = 0;
    int*      bucket = (int*)d_ws;             u += (size_t)NBUCK * BCAP;
    int*      bcur   = (int*)d_ws + u;         u += NBUCK + 4;
    int*      rowptr = (int*)d_ws + u;         u += N_NODES + 1;
    int*      csr    = (int*)d_ws + u;         u += E_EDGES;
    u = (u + 3) & ~(size_t)3;                  // 16B align
    ushort_t* Wt1    = (ushort_t*)((int*)d_ws + u); u += 128 * 128 / 2;
    ushort_t* Wt2    = (ushort_t*)((int*)d_ws + u); u += 80 * 64 / 2;
    uchar_t*  h1l    = (uchar_t*)((int*)d_ws + u);  u += (size_t)N_NODES * HID_C / 4;
    ushort_t* h1r    = (ushort_t*)((int*)d_ws + u); u += (size_t)N_NODES * HID_C / 2;
    uchar_t*  h2l    = (uchar_t*)((int*)d_ws + u);  u += (size_t)N_NODES * 64 / 4;
    ushort_t* h2r    = (ushort_t*)((int*)d_ws + u); u += (size_t)N_NODES * OUT_C / 2;
    if (ws_size < u * 4) return;

    hipMemsetAsync(bcur, 0, NBUCK * sizeof(int), stream);

    const int* src = ei;
    const int* dst = ei + E_EDGES;

    k_prep<<<B1_GRID + 64, 256, 0, stream>>>(src, dst, bcur, bucket, Wl1, Wr1, Wl2, Wr2, Wt1, Wt2);
    k_csr_gemm1<<<NBUCK + TILE_GRID, 256, 0, stream>>>(bucket, bcur, rowptr, csr, x, Wt1, h1l, h1r);
    k_agg1_gemm2<<<TILE_GRID, 256, 0, stream>>>(rowptr, csr, h1l, h1r, b1, Wt2, h2l, h2r);
    k_agg2<<<N_NODES / 4, 256, 0, stream>>>(rowptr, csr, h2l, h2r, b2, (float*)d_out);
}

// Round 3
// 264.600 us; speedup vs baseline: 1.1301x; 1.1301x over previous
//
#include <hip/hip_runtime.h>
#include <hip/hip_bf16.h>

#define N_NODES 100000
#define E_EDGES 1600000
#define IN_C 128
#define HID_C 64
#define OUT_C 40

#define NBUCK 196          // ceil(100000 / 512) buckets by dst>>9
#define BCAP 9216          // mean 8192 + 11 sigma
#define B1_EPT 16
#define B1_CHUNK (256 * B1_EPT)   // 4096 edges per block
#define B1_GRID ((E_EDGES + B1_CHUNK - 1) / B1_CHUNK)
#define TILE_GRID ((N_NODES + 63) / 64)

typedef unsigned short ushort_t;
typedef unsigned int uint_t;
typedef unsigned char uchar_t;
typedef __attribute__((ext_vector_type(8))) short bf16x8;
typedef __attribute__((ext_vector_type(4))) float f32x4;
typedef __attribute__((ext_vector_type(2))) float f32x2;

__device__ __forceinline__ float bfu2f(ushort_t u) {
    return __uint_as_float(((uint_t)u) << 16);
}
__device__ __forceinline__ ushort_t f2bfu(float f) {   // RNE
    uint_t u = __float_as_uint(f);
    return (ushort_t)((u + 0x7FFFu + ((u >> 16) & 1u)) >> 16);
}
__device__ __forceinline__ uchar_t f2fp8(float f) {    // e4m3 via HW cvt
    int p = __builtin_amdgcn_cvt_pk_fp8_f32(f, f, 0, false);
    return (uchar_t)(p & 0xff);
}

// ================================================================ K1: bucketize (blocks 0..B1_GRID-1) || GEMM1 (rest)
// GEMM1 depends only on x and W1 -> overlap it with the edge bucketize instead of serializing.
// GEMM1 blocks stage W1 from f32 global directly (64KB, L2-resident after first block).
struct SmemPrep {
    int cnt[NBUCK];
    int base[NBUCK];
};
struct SmemGemm1 {
    ushort_t xs[64 * 136];
    ushort_t wsm[128 * 136];
};
union SmemK1 {
    SmemPrep p;
    SmemGemm1 g;
};

__global__ __launch_bounds__(256) void k_prep_gemm1(const int* __restrict__ src, const int* __restrict__ dst,
                                                    int* __restrict__ bcur, int* __restrict__ bucket,
                                                    const float* __restrict__ Wl1, const float* __restrict__ Wr1,
                                                    const float* __restrict__ x,
                                                    uchar_t* __restrict__ h1l, ushort_t* __restrict__ h1r) {
    __shared__ SmemK1 sm;
    const int t = threadIdx.x;

    if (blockIdx.x < B1_GRID) {
        // ---- bucketize edges by dst>>9 (packed: src | dlocal<<17)
        const int e0 = blockIdx.x * B1_CHUNK;
        for (int i = t; i < NBUCK; i += 256) sm.p.cnt[i] = 0;
        __syncthreads();

        int myp[B1_EPT];
        int myb[B1_EPT];
#pragma unroll
        for (int j = 0; j < B1_EPT; ++j) {
            int e = e0 + t + j * 256;
            if (e < E_EDGES) {
                int d = dst[e];
                myp[j] = src[e] | ((d & 511) << 17);
                myb[j] = d >> 9;
                atomicAdd(&sm.p.cnt[myb[j]], 1);
            } else {
                myb[j] = -1;
            }
        }
        __syncthreads();
        for (int i = t; i < NBUCK; i += 256) {
            sm.p.base[i] = atomicAdd(&bcur[i], sm.p.cnt[i]);
            sm.p.cnt[i] = 0;
        }
        __syncthreads();
#pragma unroll
        for (int j = 0; j < B1_EPT; ++j) {
            if (myb[j] >= 0) {
                int b = myb[j];
                int loc = atomicAdd(&sm.p.cnt[b], 1);
                int pos = sm.p.base[b] + loc;
                if (pos < BCAP) bucket[(size_t)b * BCAP + pos] = myp[j];
            }
        }
    } else {
        // ---- GEMM1 (MFMA): [h1l(fp8) | h1r(bf16)] = x @ [Wl1|Wr1]
        const int row_base = (blockIdx.x - B1_GRID) * 64;

        // stage W1 from f32 global: wsm[n*136+k] = bf16(W[k][n]); n<64 -> Wl1, else Wr1.
        // i = n fastest -> wave-uniform l/r branch, coalesced 256B reads (L2-hit after first block).
        for (int i = t; i < 128 * 64; i += 256) {
            int n = i & 127, kp = i >> 7;      // kp in [0,64), k = 2*kp
            const float* W = (n < 64) ? Wl1 : Wr1;
            int nn = n & 63;
            float va = W[(2 * kp) * 64 + nn];
            float vb = W[(2 * kp + 1) * 64 + nn];
            uint_t u = (uint_t)f2bfu(va) | ((uint_t)f2bfu(vb) << 16);
            *(uint_t*)(sm.g.wsm + n * 136 + 2 * kp) = u;
        }
        for (int i = t; i < 64 * 32; i += 256) {
            int row = i >> 5, seg = i & 31;
            int gr = row_base + row;
            float4 v = make_float4(0.f, 0.f, 0.f, 0.f);
            if (gr < N_NODES) v = *(const float4*)(x + (size_t)gr * IN_C + seg * 4);
            ushort4 u;
            u.x = f2bfu(v.x); u.y = f2bfu(v.y); u.z = f2bfu(v.z); u.w = f2bfu(v.w);
            *(ushort4*)(sm.g.xs + row * 136 + seg * 4) = u;
        }
        __syncthreads();

        const int wv = t >> 6, lane = t & 63;
        const int m = lane & 15, quad = lane >> 4;
        const int m0 = wv * 16;

        bf16x8 a[4];
#pragma unroll
        for (int kk = 0; kk < 4; ++kk)
            a[kk] = *(const bf16x8*)(sm.g.xs + (m0 + m) * 136 + kk * 32 + quad * 8);

        f32x4 acc[8];
#pragma unroll
        for (int nt = 0; nt < 8; ++nt) acc[nt] = (f32x4){0.f, 0.f, 0.f, 0.f};

#pragma unroll
        for (int nt = 0; nt < 8; ++nt) {
#pragma unroll
            for (int kk = 0; kk < 4; ++kk) {
                bf16x8 b = *(const bf16x8*)(sm.g.wsm + (nt * 16 + m) * 136 + kk * 32 + quad * 8);
                acc[nt] = __builtin_amdgcn_mfma_f32_16x16x32_bf16(a[kk], b, acc[nt], 0, 0, 0);
            }
        }

        const int grow_base = row_base + m0 + quad * 4;
#pragma unroll
        for (int r = 0; r < 4; ++r) {
            int grow = grow_base + r;
            if (grow < N_NODES) {
#pragma unroll
                for (int nt = 0; nt < 4; ++nt)
                    h1l[(size_t)grow * HID_C + nt * 16 + m] = f2fp8(acc[nt][r]);
#pragma unroll
                for (int nt = 4; nt < 8; ++nt)
                    h1r[(size_t)grow * HID_C + (nt - 4) * 16 + m] = f2bfu(acc[nt][r]);
            }
        }
    }
}

// ================================================================ K2: per-bucket counting sort, 512 threads (1 thread/bin)
// || Wt2 prep (blocks >= NBUCK). csr stores BYTE offsets (src*64) as in the proven gather kernels.
__global__ __launch_bounds__(512) void k_csr(const int* __restrict__ bucket, const int* __restrict__ bcur,
                                             int* __restrict__ rowptr, int* __restrict__ csr,
                                             const float* __restrict__ Wl2, const float* __restrict__ Wr2,
                                             ushort_t* __restrict__ Wt2) {
    const int t = threadIdx.x;
    if (blockIdx.x >= NBUCK) {
        // ---- Wt2 prep: bf16, transposed, l|r concatenated
        int i = (blockIdx.x - NBUCK) * 512 + t;
        if (i < 80 * 64) {
            int n = i >> 6, k = i & 63;
            float v = (n < 40) ? Wl2[k * 40 + n] : Wr2[k * 40 + (n - 40)];
            Wt2[n * 64 + k] = f2bfu(v);
        }
        return;
    }

    __shared__ int red[512];
    __shared__ int hist[512];
    __shared__ int scan[512];
    __shared__ int cur[512];
    __shared__ int csrbuf[BCAP];

    const int b = blockIdx.x;
    const int n0 = b << 9;
    const int nb = min(512, N_NODES - n0);
    const int sz = min(bcur[b], BCAP);
    const int* bdata = bucket + (size_t)b * BCAP;

    // cbase = sum of bucket sizes before b
    red[t] = (t < b) ? min(bcur[t], BCAP) : 0;
    __syncthreads();
    for (int off = 256; off > 0; off >>= 1) {
        if (t < off) red[t] += red[t + off];
        __syncthreads();
    }
    const int cbase = red[0];

    hist[t] = 0;
    __syncthreads();
    for (int i = t; i < sz; i += 512) atomicAdd(&hist[bdata[i] >> 17], 1);
    __syncthreads();

    // inclusive Hillis-Steele scan over 512 bins, 1 thread/bin
    scan[t] = hist[t];
    __syncthreads();
    for (int off = 1; off < 512; off <<= 1) {
        int add = (t >= off) ? scan[t - off] : 0;
        __syncthreads();
        scan[t] += add;
        __syncthreads();
    }

    int exc = scan[t] - hist[t];
    cur[t] = exc;
    if (t < nb) rowptr[n0 + t] = cbase + exc;
    __syncthreads();

    for (int i = t; i < sz; i += 512) {
        int p = bdata[i];
        int pos = atomicAdd(&cur[p >> 17], 1);
        csrbuf[pos] = (p & 0x1FFFF) << 6;   // byte offset into 64B-stride feature rows
    }
    __syncthreads();
    for (int i = t; i < sz; i += 512)
        csr[cbase + i] = csrbuf[i];
    if (b == NBUCK - 1 && t == 0) rowptr[N_NODES] = cbase + sz;
}

// ================================================================ K3: fused agg1 + gemm2  (round-0 proven body)
// Phase A: 4 waves x 16 serial rows: 8-slot fp8 gather (csr byte-offsets), relu(mean+root+b1) -> LDS bf16 tile
// Phase B: gemm2 MFMA from LDS: [h2l(fp8,stride64) | h2r(bf16)] = hid @ [Wl2|Wr2]
__global__ __launch_bounds__(256) void k_agg1_gemm2(const int* __restrict__ rowptr, const int* __restrict__ csr,
                                                    const uchar_t* __restrict__ h1l, const ushort_t* __restrict__ h1r,
                                                    const float* __restrict__ b1, const ushort_t* __restrict__ Wt,
                                                    uchar_t* __restrict__ h2l, ushort_t* __restrict__ h2r) {
    __shared__ ushort_t hs[64 * 72];     // hid tile, bf16
    __shared__ ushort_t wsm[80 * 72];    // Wt2
    const int t = threadIdx.x;
    const int row_base = blockIdx.x * 64;
    const int wv = t >> 6, lane = t & 63;
    const int slot = lane >> 3;
    const int part = lane & 7;

    // stage Wt2 (consumed after the phase-boundary syncthreads)
    for (int i = t; i < 80 * 8; i += 256) {
        int n = i >> 3, seg = i & 7;
        uint4 v = *(const uint4*)(Wt + n * 64 + seg * 8);
        *(uint4*)(wsm + n * 72 + seg * 8) = v;
    }

    // ---- phase A: aggregate 16 rows per wave
    float4 bb0, bb1;
    if (slot == 0) {
        bb0 = *(const float4*)(b1 + part * 8);
        bb1 = *(const float4*)(b1 + part * 8 + 4);
    }
    for (int r16 = 0; r16 < 16; ++r16) {
        int lrow = wv * 16 + r16;
        int row = row_base + lrow;
        if (row < N_NODES) {
            int2 rp = *(const int2*)(rowptr + row);
            int start = rp.x, end = rp.y;
            f32x2 acc[4];
#pragma unroll
            for (int j = 0; j < 4; ++j) acc[j] = (f32x2){0.f, 0.f};

            int base = start;
            for (; base + 8 <= end; base += 8) {
                int s = csr[base + slot];                       // byte offset
                uint2 u = *(const uint2*)(h1l + s + part * 8);
                acc[0] += __builtin_amdgcn_cvt_pk_f32_fp8(u.x, false);
                acc[1] += __builtin_amdgcn_cvt_pk_f32_fp8(u.x, true);
                acc[2] += __builtin_amdgcn_cvt_pk_f32_fp8(u.y, false);
                acc[3] += __builtin_amdgcn_cvt_pk_f32_fp8(u.y, true);
            }
            if (base < end) {
                int e = base + slot;
                int s = csr[min(e, end - 1)];
                uint2 u = *(const uint2*)(h1l + s + part * 8);
                if (e >= end) { u.x = 0u; u.y = 0u; }
                acc[0] += __builtin_amdgcn_cvt_pk_f32_fp8(u.x, false);
                acc[1] += __builtin_amdgcn_cvt_pk_f32_fp8(u.x, true);
                acc[2] += __builtin_amdgcn_cvt_pk_f32_fp8(u.y, false);
                acc[3] += __builtin_amdgcn_cvt_pk_f32_fp8(u.y, true);
            }
#pragma unroll
            for (int off = 8; off <= 32; off <<= 1) {
#pragma unroll
                for (int j = 0; j < 4; ++j) {
                    f32x2 tt;
                    tt.x = __shfl_xor(acc[j].x, off);
                    tt.y = __shfl_xor(acc[j].y, off);
                    acc[j] += tt;
                }
            }
            if (slot == 0) {
                float inv = __builtin_amdgcn_rcpf(fmaxf((float)(end - start), 1.0f));
                ushort_t rr[8];
                *(uint4*)rr = *(const uint4*)(h1r + (size_t)row * HID_C + part * 8);
                ushort_t o[8];
                o[0] = f2bfu(fmaxf(acc[0].x * inv + bfu2f(rr[0]) + bb0.x, 0.f));
                o[1] = f2bfu(fmaxf(acc[0].y * inv + bfu2f(rr[1]) + bb0.y, 0.f));
                o[2] = f2bfu(fmaxf(acc[1].x * inv + bfu2f(rr[2]) + bb0.z, 0.f));
                o[3] = f2bfu(fmaxf(acc[1].y * inv + bfu2f(rr[3]) + bb0.w, 0.f));
                o[4] = f2bfu(fmaxf(acc[2].x * inv + bfu2f(rr[4]) + bb1.x, 0.f));
                o[5] = f2bfu(fmaxf(acc[2].y * inv + bfu2f(rr[5]) + bb1.y, 0.f));
                o[6] = f2bfu(fmaxf(acc[3].x * inv + bfu2f(rr[6]) + bb1.z, 0.f));
                o[7] = f2bfu(fmaxf(acc[3].y * inv + bfu2f(rr[7]) + bb1.w, 0.f));
                *(uint4*)(hs + lrow * 72 + part * 8) = *(const uint4*)o;
            }
        } else if (slot == 0) {
            uint4 z = make_uint4(0u, 0u, 0u, 0u);
            *(uint4*)(hs + lrow * 72 + part * 8) = z;
        }
    }
    __syncthreads();

    // ---- phase B: gemm2 MFMA from LDS
    const int m = lane & 15, quad = lane >> 4;
    const int m0 = wv * 16;

    bf16x8 a[2];
#pragma unroll
    for (int kk = 0; kk < 2; ++kk)
        a[kk] = *(const bf16x8*)(hs + (m0 + m) * 72 + kk * 32 + quad * 8);

    f32x4 acc[5];
#pragma unroll
    for (int nt = 0; nt < 5; ++nt) acc[nt] = (f32x4){0.f, 0.f, 0.f, 0.f};

#pragma unroll
    for (int nt = 0; nt < 5; ++nt) {
#pragma unroll
        for (int kk = 0; kk < 2; ++kk) {
            bf16x8 b = *(const bf16x8*)(wsm + (nt * 16 + m) * 72 + kk * 32 + quad * 8);
            acc[nt] = __builtin_amdgcn_mfma_f32_16x16x32_bf16(a[kk], b, acc[nt], 0, 0, 0);
        }
    }

    const int grow_base = row_base + m0 + quad * 4;
#pragma unroll
    for (int r = 0; r < 4; ++r) {
        int grow = grow_base + r;
        if (grow < N_NODES) {
#pragma unroll
            for (int nt = 0; nt < 5; ++nt) {
                int col = nt * 16 + m;
                float v = acc[nt][r];
                if (col < OUT_C) h2l[(size_t)grow * 64 + col] = f2fp8(v);
                else             h2r[(size_t)grow * OUT_C + (col - OUT_C)] = f2bfu(v);
            }
        }
    }
}

// ================================================================ agg2: 8-slot uint2 gather of fp8 h2l (40B in 64B stride)
// csr byte-offsets; packed-f32 accumulation; static-xor reduce; native-exp log_softmax (round-0 proven body)
__global__ __launch_bounds__(256) void k_agg2(const int* __restrict__ rowptr, const int* __restrict__ csr,
                                              const uchar_t* __restrict__ h2l, const ushort_t* __restrict__ h2r,
                                              const float* __restrict__ b2, float* __restrict__ out) {
    int row = (blockIdx.x * 256 + threadIdx.x) >> 6;
    int lane = threadIdx.x & 63;
    if (row >= N_NODES) return;
    int2 rp = *(const int2*)(rowptr + row);
    int start = rp.x, end = rp.y;
    const int slot = lane >> 3;
    const int part = lane & 7;
    f32x2 acc[4];
#pragma unroll
    for (int j = 0; j < 4; ++j) acc[j] = (f32x2){0.f, 0.f};

    int base = start;
    for (; base + 8 <= end; base += 8) {
        int s = csr[base + slot];                       // byte offset
        uint2 u = *(const uint2*)(h2l + s + part * 8);
        acc[0] += __builtin_amdgcn_cvt_pk_f32_fp8(u.x, false);
        acc[1] += __builtin_amdgcn_cvt_pk_f32_fp8(u.x, true);
        acc[2] += __builtin_amdgcn_cvt_pk_f32_fp8(u.y, false);
        acc[3] += __builtin_amdgcn_cvt_pk_f32_fp8(u.y, true);
    }
    if (base < end) {
        int e = base + slot;
        int s = csr[min(e, end - 1)];
        uint2 u = *(const uint2*)(h2l + s + part * 8);
        if (e >= end) { u.x = 0u; u.y = 0u; }
        acc[0] += __builtin_amdgcn_cvt_pk_f32_fp8(u.x, false);
        acc[1] += __builtin_amdgcn_cvt_pk_f32_fp8(u.x, true);
        acc[2] += __builtin_amdgcn_cvt_pk_f32_fp8(u.y, false);
        acc[3] += __builtin_amdgcn_cvt_pk_f32_fp8(u.y, true);
    }
#pragma unroll
    for (int off = 8; off <= 32; off <<= 1) {
#pragma unroll
        for (int j = 0; j < 4; ++j) {
            f32x2 tt;
            tt.x = __shfl_xor(acc[j].x, off);
            tt.y = __shfl_xor(acc[j].y, off);
            acc[j] += tt;
        }
    }

    // slot-0 lanes with part<5 hold channels part*8 .. part*8+7
    const bool fin = (slot == 0) && (part < 5);
    float inv = __builtin_amdgcn_rcpf(fmaxf((float)(end - start), 1.0f));
    f32x2 v2[4];
    if (fin) {
        size_t bi = (size_t)row * OUT_C + part * 8;
        ushort_t rr[8];
        *(uint2*)&rr[0] = *(const uint2*)(h2r + bi);
        *(uint2*)&rr[4] = *(const uint2*)(h2r + bi + 4);
        float4 bb0 = *(const float4*)(b2 + part * 8);
        float4 bb1 = *(const float4*)(b2 + part * 8 + 4);
        v2[0] = (f32x2){acc[0].x * inv + bfu2f(rr[0]) + bb0.x, acc[0].y * inv + bfu2f(rr[1]) + bb0.y};
        v2[1] = (f32x2){acc[1].x * inv + bfu2f(rr[2]) + bb0.z, acc[1].y * inv + bfu2f(rr[3]) + bb0.w};
        v2[2] = (f32x2){acc[2].x * inv + bfu2f(rr[4]) + bb1.x, acc[2].y * inv + bfu2f(rr[5]) + bb1.y};
        v2[3] = (f32x2){acc[3].x * inv + bfu2f(rr[6]) + bb1.z, acc[3].y * inv + bfu2f(rr[7]) + bb1.w};
    } else {
#pragma unroll
        for (int j = 0; j < 4; ++j) v2[j] = (f32x2){-1e30f, -1e30f};
    }
    // softmax stats within the 8-lane group (non-fin lanes compute garbage, never write)
    f32x2 m2;
    m2.x = fmaxf(fmaxf(v2[0].x, v2[1].x), fmaxf(v2[2].x, v2[3].x));
    m2.y = fmaxf(fmaxf(v2[0].y, v2[1].y), fmaxf(v2[2].y, v2[3].y));
    float pm = fmaxf(m2.x, m2.y);
#pragma unroll
    for (int off = 1; off <= 4; off <<= 1) pm = fmaxf(pm, __shfl_xor(pm, off));
    float es = 0.f;
#pragma unroll
    for (int j = 0; j < 4; ++j) {
        es += __expf(v2[j].x - pm);
        es += __expf(v2[j].y - pm);
    }
#pragma unroll
    for (int off = 1; off <= 4; off <<= 1) es += __shfl_xor(es, off);
    float ls = __logf(es);
    if (fin) {
        size_t bo = (size_t)row * OUT_C + part * 8;
        *(float4*)(out + bo) = make_float4(v2[0].x - pm - ls, v2[0].y - pm - ls,
                                           v2[1].x - pm - ls, v2[1].y - pm - ls);
        *(float4*)(out + bo + 4) = make_float4(v2[2].x - pm - ls, v2[2].y - pm - ls,
                                               v2[3].x - pm - ls, v2[3].y - pm - ls);
    }
}

// ----------------------------------------------------------------
extern "C" void kernel_launch(void* const* d_in, const int* in_sizes, int n_in,
                              void* d_out, int out_size, void* d_ws, size_t ws_size,
                              hipStream_t stream) {
    const float* x   = (const float*)d_in[0];
    const int*   ei  = (const int*)d_in[1];
    const float* Wl1 = (const float*)d_in[2];
    const float* b1  = (const float*)d_in[3];
    const float* Wr1 = (const float*)d_in[4];
    const float* Wl2 = (const float*)d_in[5];
    const float* b2  = (const float*)d_in[6];
    const float* Wr2 = (const float*)d_in[7];

    // ws layout (4B units): bucket int[196*9216] | bcur | rowptr[N+1] | csr[E] | [align16] |
    //   Wt2 bf16[80*64] | h1l fp8[N*64] | h1r bf16[N*64] | h2l fp8[N*64] | h2r bf16[N*40]
    size_t u = 0;
    int*      bucket = (int*)d_ws;             u += (size_t)NBUCK * BCAP;
    int*      bcur   = (int*)d_ws + u;         u += NBUCK + 4;
    int*      rowptr = (int*)d_ws + u;         u += N_NODES + 1;
    int*      csr    = (int*)d_ws + u;         u += E_EDGES;
    u = (u + 3) & ~(size_t)3;                  // 16B align
    ushort_t* Wt2    = (ushort_t*)((int*)d_ws + u); u += 80 * 64 / 2;
    uchar_t*  h1l    = (uchar_t*)((int*)d_ws + u);  u += (size_t)N_NODES * HID_C / 4;
    ushort_t* h1r    = (ushort_t*)((int*)d_ws + u); u += (size_t)N_NODES * HID_C / 2;
    uchar_t*  h2l    = (uchar_t*)((int*)d_ws + u);  u += (size_t)N_NODES * 64 / 4;
    ushort_t* h2r    = (ushort_t*)((int*)d_ws + u); u += (size_t)N_NODES * OUT_C / 2;
    if (ws_size < u * 4) return;

    hipMemsetAsync(bcur, 0, NBUCK * sizeof(int), stream);

    const int* src = ei;
    const int* dst = ei + E_EDGES;

    k_prep_gemm1<<<B1_GRID + TILE_GRID, 256, 0, stream>>>(src, dst, bcur, bucket, Wl1, Wr1, x, h1l, h1r);
    k_csr<<<NBUCK + 10, 512, 0, stream>>>(bucket, bcur, rowptr, csr, Wl2, Wr2, Wt2);
    k_agg1_gemm2<<<TILE_GRID, 256, 0, stream>>>(rowptr, csr, h1l, h1r, b1, Wt2, h2l, h2r);
    k_agg2<<<N_NODES / 4, 256, 0, stream>>>(rowptr, csr, h2l, h2r, b2, (float*)d_out);
}